// Round 6
// baseline (848.145 us; speedup 1.0000x reference)
//
#include <hip/hip_runtime.h>
#include <hip/hip_bf16.h>

// Problem constants (from reference)
#define NUM_USERS 100000
#define NUM_ITEMS 50000
#define N_NODES   150000   // NUM_USERS + NUM_ITEMS
#define EMB       64
#define NNZ       2400000
#define BATCH     16384
#define D_CAT     384      // EMB*3*2
#define BSHIFT    5        // 32 rows per bucket
#define NBUCK     ((N_NODES + 31) >> 5)   // 4688

// ---- bf16 helpers (bit-level, RN-even for f32->bf16) -----------------------
__device__ __forceinline__ unsigned short f2bf(float f) {
    unsigned u = __float_as_uint(f);
    unsigned r = u + 0x7fffu + ((u >> 16) & 1u);
    return (unsigned short)(r >> 16);
}
__device__ __forceinline__ float bflo(unsigned u) { return __uint_as_float(u << 16); }
__device__ __forceinline__ float bfhi(unsigned u) { return __uint_as_float(u & 0xffff0000u); }

// ---------------------------------------------------------------------------
// CSR build step 1: histogram of row indices. cnt must be zeroed first.
// 150000 counters -> low contention (measured fast in rounds 3/5).
// ---------------------------------------------------------------------------
__global__ __launch_bounds__(256) void hist_rows(const int* __restrict__ rows,
                                                 int* __restrict__ cnt, int nnz) {
    int i = blockIdx.x * 256 + threadIdx.x;
    if (i < nnz) atomicAdd(&cnt[rows[i]], 1);
}

// ---------------------------------------------------------------------------
// CSR build step 2a: per-block (1024-elem) exclusive scan of cnt -> partial,
// block totals -> blockSums. partial stored into row_ptr (temporarily).
// ---------------------------------------------------------------------------
__global__ __launch_bounds__(1024) void scan1(const int* __restrict__ cnt,
                                              int* __restrict__ partial,
                                              int* __restrict__ blockSums, int n) {
    __shared__ int s[1024];
    int t = threadIdx.x;
    int i = blockIdx.x * 1024 + t;
    int x = (i < n) ? cnt[i] : 0;
    s[t] = x;
    __syncthreads();
#pragma unroll
    for (int off = 1; off < 1024; off <<= 1) {
        int v = (t >= off) ? s[t - off] : 0;
        __syncthreads();
        s[t] += v;
        __syncthreads();
    }
    if (i < n) partial[i] = s[t] - x;          // exclusive within block
    if (t == 1023) blockSums[blockIdx.x] = s[t];
}

// ---------------------------------------------------------------------------
// CSR build step 2b: single-block exclusive scan of blockSums (in place).
// ---------------------------------------------------------------------------
__global__ __launch_bounds__(1024) void scan2(int* __restrict__ blockSums, int nb) {
    __shared__ int s[1024];
    int t = threadIdx.x;
    int x = (t < nb) ? blockSums[t] : 0;
    s[t] = x;
    __syncthreads();
#pragma unroll
    for (int off = 1; off < 1024; off <<= 1) {
        int v = (t >= off) ? s[t - off] : 0;
        __syncthreads();
        s[t] += v;
        __syncthreads();
    }
    if (t < nb) blockSums[t] = s[t] - x;       // exclusive
}

// ---------------------------------------------------------------------------
// CSR build step 2c: row_ptr[i] = partial[i] + blockOffs[blk]. Also emits the
// bucket-granular tail pointers boffs[b] = row_ptr[b*32] for the coarse bin,
// and row_ptr[n] = nnz.
// ---------------------------------------------------------------------------
__global__ __launch_bounds__(1024) void scan3(int* __restrict__ row_ptr,
                                              int* __restrict__ boffs,
                                              const int* __restrict__ blockSums,
                                              int n, int nnz) {
    int t = threadIdx.x;
    int i = blockIdx.x * 1024 + t;
    if (i < n) {
        int v = row_ptr[i] + blockSums[blockIdx.x];
        row_ptr[i] = v;
        if ((i & 31) == 0) boffs[i >> BSHIFT] = v;
    }
    if (i == 0) row_ptr[n] = nnz;
}

// ---------------------------------------------------------------------------
// Pass B: coarse bin. Scatter each edge to its 32-row bucket's tail.
// Active write set = 4688 tail lines (~600 KB, L2-resident) -> consecutive
// slots of a line are filled close in time -> write combining (vs the round-5
// fully-random scatter at 149 MB writeback).
// ---------------------------------------------------------------------------
__global__ __launch_bounds__(256) void coarse_bin(const int* __restrict__ rows,
                                                  const int* __restrict__ cols,
                                                  const float* __restrict__ vals,
                                                  int* __restrict__ boffs,
                                                  int* __restrict__ rows2,
                                                  int2* __restrict__ pv, int nnz) {
    int i = blockIdx.x * 256 + threadIdx.x;
    if (i >= nnz) return;
    int r = rows[i];
    int pos = atomicAdd(&boffs[r >> BSHIFT], 1);
    rows2[pos] = r;
    pv[pos] = make_int2(cols[i], __float_as_int(vals[i]));
}

// ---------------------------------------------------------------------------
// Pass C: fine scatter within a bucket. One block per bucket; fine counters
// live in LDS (atomic returns position, no global round-trip); output region
// is a ~4 KB window written by this CU only -> ~1x write amplification.
// ---------------------------------------------------------------------------
__global__ __launch_bounds__(256) void fine_scatter(const int* __restrict__ row_ptr,
                                                    const int* __restrict__ rows2,
                                                    const int2* __restrict__ pv,
                                                    int2* __restrict__ packed) {
    __shared__ int loff[33];
    int b = blockIdx.x;
    int r0 = b << BSHIFT;
    int nr = N_NODES - r0 < 32 ? N_NODES - r0 : 32;
    int tid = threadIdx.x;
    if (tid <= 32) {
        int rr = r0 + tid;
        loff[tid] = row_ptr[rr > N_NODES ? N_NODES : rr];
    }
    __syncthreads();
    int lo = loff[0];
    int hi = loff[nr];
    for (int i = lo + tid; i < hi; i += 256) {
        int r = rows2[i];
        int pos = atomicAdd(&loff[r - r0], 1);
        packed[pos] = pv[i];
    }
}

// ---------------------------------------------------------------------------
// Convert concat(uEmb,iEmb) fp32 -> bf16 table (4 elems / thread)
// ---------------------------------------------------------------------------
__global__ __launch_bounds__(256) void cvt_feat0(const float4* __restrict__ a, int na4,
                                                 const float4* __restrict__ b, int nb4,
                                                 ushort4* __restrict__ dst) {
    int i = blockIdx.x * 256 + threadIdx.x;
    if (i >= na4 + nb4) return;
    float4 v = (i < na4) ? a[i] : b[i - na4];
    ushort4 o;
    o.x = f2bf(v.x); o.y = f2bf(v.y); o.z = f2bf(v.z); o.w = f2bf(v.w);
    dst[i] = o;
}

// ---------------------------------------------------------------------------
// SPMM (CSR): h[r] = x[r] + sum_edges v * x[c]  (bf16 gathers, fp32 acc).
// One wave per row; half-wave per edge. (Unchanged from round 5.)
// ---------------------------------------------------------------------------
__global__ __launch_bounds__(256) void spmm_csr(const int* __restrict__ row_ptr,
                                                const int2* __restrict__ packed,
                                                const unsigned int* __restrict__ xh, // bf16x2, stride 32/row
                                                float2* __restrict__ h,              // stride 32/row
                                                int n_rows) {
    int tid = threadIdx.x;
    int lane = tid & 63;
    int wave = tid >> 6;
    int half = lane >> 5;
    int k = lane & 31;
    int r = blockIdx.x * 4 + wave;
    if (r >= n_rows) return;

    unsigned su = xh[(size_t)r * 32 + k];
    float2 acc;
    acc.x = half ? 0.f : bflo(su);
    acc.y = half ? 0.f : bfhi(su);

    int e = row_ptr[r] + half;
    int end = row_ptr[r + 1];
    for (; e + 6 < end; e += 8) {
        int2 p0 = packed[e + 0];
        int2 p1 = packed[e + 2];
        int2 p2 = packed[e + 4];
        int2 p3 = packed[e + 6];
        unsigned x0 = xh[(size_t)p0.x * 32 + k];
        unsigned x1 = xh[(size_t)p1.x * 32 + k];
        unsigned x2 = xh[(size_t)p2.x * 32 + k];
        unsigned x3 = xh[(size_t)p3.x * 32 + k];
        float v0 = __int_as_float(p0.y), v1 = __int_as_float(p1.y);
        float v2 = __int_as_float(p2.y), v3 = __int_as_float(p3.y);
        acc.x = fmaf(v0, bflo(x0), acc.x); acc.y = fmaf(v0, bfhi(x0), acc.y);
        acc.x = fmaf(v1, bflo(x1), acc.x); acc.y = fmaf(v1, bfhi(x1), acc.y);
        acc.x = fmaf(v2, bflo(x2), acc.x); acc.y = fmaf(v2, bfhi(x2), acc.y);
        acc.x = fmaf(v3, bflo(x3), acc.x); acc.y = fmaf(v3, bfhi(x3), acc.y);
    }
    for (; e < end; e += 2) {
        int2 p = packed[e];
        unsigned x = xh[(size_t)p.x * 32 + k];
        float v = __int_as_float(p.y);
        acc.x = fmaf(v, bflo(x), acc.x);
        acc.y = fmaf(v, bfhi(x), acc.y);
    }

    acc.x += __shfl_xor(acc.x, 32, 64);
    acc.y += __shfl_xor(acc.y, 32, 64);
    if (!half) h[(size_t)r * 32 + k] = acc;
}

// ---------------------------------------------------------------------------
// out_bf16[r][c] = relu( b[c] + sum_{k<64} X[r][k] * W[k][c] )
// ---------------------------------------------------------------------------
__global__ __launch_bounds__(256) void gemm64_relu_bf16(const float* __restrict__ X,
                                                        const float* __restrict__ W,
                                                        const float* __restrict__ bia,
                                                        unsigned short* __restrict__ outh,
                                                        int n_rows) {
    __shared__ float Wl[64 * 64];
    int tid = threadIdx.x;
    int lane = tid & 63;
    int wave = tid >> 6;
    int r0 = blockIdx.x * 64 + wave * 16;
    int last = n_rows - 1;
    for (int i = tid; i < 64 * 64; i += 256) Wl[i] = W[i];
    __syncthreads();

    const float* rowp[16];
#pragma unroll
    for (int i = 0; i < 16; ++i) {
        int r = r0 + i;
        r = r > last ? last : r;
        rowp[i] = X + (size_t)r * 64;
    }
    float acc[16];
    float bv = bia[lane];
#pragma unroll
    for (int i = 0; i < 16; ++i) acc[i] = bv;

#pragma unroll 1
    for (int k = 0; k < 64; k += 4) {
        float w0 = Wl[(k + 0) * 64 + lane];
        float w1 = Wl[(k + 1) * 64 + lane];
        float w2 = Wl[(k + 2) * 64 + lane];
        float w3 = Wl[(k + 3) * 64 + lane];
#pragma unroll
        for (int i = 0; i < 16; ++i) {
            float4 e = *(const float4*)(rowp[i] + k);
            acc[i] = fmaf(e.x, w0, acc[i]);
            acc[i] = fmaf(e.y, w1, acc[i]);
            acc[i] = fmaf(e.z, w2, acc[i]);
            acc[i] = fmaf(e.w, w3, acc[i]);
        }
    }
#pragma unroll
    for (int i = 0; i < 16; ++i) {
        int r = r0 + i;
        if (r < n_rows) outh[(size_t)r * 64 + lane] = f2bf(fmaxf(acc[i], 0.f));
    }
}

// ---------------------------------------------------------------------------
// Gather concatenated per-sample features -> bf16 E (one 384-thread block/row)
// ---------------------------------------------------------------------------
__global__ __launch_bounds__(384) void gather_e(const int* __restrict__ userIdx,
                                                const int* __restrict__ itemIdx,
                                                const float* __restrict__ uEmb,
                                                const float* __restrict__ iEmb,
                                                const unsigned short* __restrict__ feat1h,
                                                const unsigned short* __restrict__ feat2h,
                                                unsigned short* __restrict__ E) {
    int b = blockIdx.x;
    int j = threadIdx.x;          // 0..383
    int half = j >= 192;
    int jj = half ? (j - 192) : j;
    int seg = jj >> 6;
    int k = jj & 63;
    unsigned short v;
    if (half == 0) {
        int u = userIdx[b];
        if (seg == 0)      v = f2bf(uEmb[(size_t)u * 64 + k]);
        else if (seg == 1) v = feat1h[(size_t)u * 64 + k];
        else               v = feat2h[(size_t)u * 64 + k];
    } else {
        int it = itemIdx[b];
        if (seg == 0)      v = f2bf(iEmb[(size_t)it * 64 + k]);
        else if (seg == 1) v = feat1h[(size_t)(it + NUM_USERS) * 64 + k];
        else               v = feat2h[(size_t)(it + NUM_USERS) * 64 + k];
    }
    E[(size_t)b * D_CAT + j] = v;
}

// ---------------------------------------------------------------------------
// H1[r][c] = relu( b1[c] + sum_{k<384} E[r][k] * W1[k][c] ), E bf16.
// ---------------------------------------------------------------------------
__global__ __launch_bounds__(256) void gemm384_bf16_relu(const unsigned short* __restrict__ E,
                                                         const float* __restrict__ W,
                                                         const float* __restrict__ bia,
                                                         float* __restrict__ H1,
                                                         int n_rows) {
    __shared__ float Wl[128 * 64];   // 32 KB
    int tid = threadIdx.x;
    int lane = tid & 63;
    int wave = tid >> 6;
    int r0 = blockIdx.x * 64 + wave * 16;
    int last = n_rows - 1;

    const unsigned short* rowp[16];
#pragma unroll
    for (int i = 0; i < 16; ++i) {
        int r = r0 + i;
        r = r > last ? last : r;
        rowp[i] = E + (size_t)r * D_CAT;
    }
    float acc[16];
    float bv = bia[lane];
#pragma unroll
    for (int i = 0; i < 16; ++i) acc[i] = bv;

    for (int k0 = 0; k0 < D_CAT; k0 += 128) {
        if (k0) __syncthreads();
        for (int i = tid; i < 128 * 64; i += 256) Wl[i] = W[k0 * 64 + i];
        __syncthreads();
#pragma unroll 1
        for (int k = 0; k < 128; k += 8) {
            float w0 = Wl[(k + 0) * 64 + lane];
            float w1 = Wl[(k + 1) * 64 + lane];
            float w2 = Wl[(k + 2) * 64 + lane];
            float w3 = Wl[(k + 3) * 64 + lane];
            float w4 = Wl[(k + 4) * 64 + lane];
            float w5 = Wl[(k + 5) * 64 + lane];
            float w6 = Wl[(k + 6) * 64 + lane];
            float w7 = Wl[(k + 7) * 64 + lane];
#pragma unroll
            for (int i = 0; i < 16; ++i) {
                uint4 q = *(const uint4*)(rowp[i] + k0 + k);
                acc[i] = fmaf(bflo(q.x), w0, acc[i]);
                acc[i] = fmaf(bfhi(q.x), w1, acc[i]);
                acc[i] = fmaf(bflo(q.y), w2, acc[i]);
                acc[i] = fmaf(bfhi(q.y), w3, acc[i]);
                acc[i] = fmaf(bflo(q.z), w4, acc[i]);
                acc[i] = fmaf(bfhi(q.z), w5, acc[i]);
                acc[i] = fmaf(bflo(q.w), w6, acc[i]);
                acc[i] = fmaf(bfhi(q.w), w7, acc[i]);
            }
        }
    }
#pragma unroll
    for (int i = 0; i < 16; ++i) {
        int r = r0 + i;
        if (r < n_rows) H1[(size_t)r * 64 + lane] = fmaxf(acc[i], 0.f);
    }
}

// ---------------------------------------------------------------------------
// Fused last two layers: z = H1@W2 + b2 (no relu); out = z@W3 + b3
// ---------------------------------------------------------------------------
__global__ __launch_bounds__(256) void mlp23(const float* __restrict__ H1,
                                             const float* __restrict__ W2,
                                             const float* __restrict__ b2,
                                             const float* __restrict__ W3,
                                             const float* __restrict__ b3,
                                             float* __restrict__ out) {
    __shared__ float Wl[64 * 32];
    __shared__ float w3l[32];
    __shared__ float b2l[32];
    int tid = threadIdx.x;
    for (int i = tid; i < 64 * 32; i += 256) Wl[i] = W2[i];
    if (tid < 32) { w3l[tid] = W3[tid]; b2l[tid] = b2[tid]; }
    __syncthreads();

    int lane = tid & 63;
    int wave = tid >> 6;
    int half = lane >> 5;
    int k = lane & 31;
    int gpair = blockIdx.x * 4 + wave;
    int npairs = gridDim.x * 4;
    float b3v = b3[0];
    for (int p = gpair; p * 2 < BATCH; p += npairs) {
        int r = p * 2 + half;
        float acc = b2l[k];
#pragma unroll
        for (int j = 0; j < 64; ++j)
            acc += H1[(size_t)r * 64 + j] * Wl[j * 32 + k];
        acc = acc * w3l[k];
#pragma unroll
        for (int off = 16; off; off >>= 1)
            acc += __shfl_xor(acc, off, 64);
        if (k == 0) out[r] = acc + b3v;
    }
}

// ---------------------------------------------------------------------------
extern "C" void kernel_launch(void* const* d_in, const int* in_sizes, int n_in,
                              void* d_out, int out_size, void* d_ws, size_t ws_size,
                              hipStream_t stream) {
    const int*   userIdx = (const int*)  d_in[0];
    const int*   itemIdx = (const int*)  d_in[1];
    const int*   lap_rows= (const int*)  d_in[2];
    const int*   lap_cols= (const int*)  d_in[3];
    const float* lap_vals= (const float*)d_in[4];
    const float* uEmb    = (const float*)d_in[5];
    const float* iEmb    = (const float*)d_in[6];
    const float* gW0     = (const float*)d_in[7];
    const float* gb0     = (const float*)d_in[8];
    const float* gW1     = (const float*)d_in[9];
    const float* gb1     = (const float*)d_in[10];
    const float* W1      = (const float*)d_in[11];
    const float* b1      = (const float*)d_in[12];
    const float* W2      = (const float*)d_in[13];
    const float* b2      = (const float*)d_in[14];
    const float* W3      = (const float*)d_in[15];
    const float* b3      = (const float*)d_in[16];
    float* out = (float*)d_out;

    const size_t NF = (size_t)N_NODES * EMB;              // 9.6M elements
    char* w = (char*)d_ws;
    unsigned short* bufA = (unsigned short*)w;            // feat0h/feat1h (19.2 MB)
    unsigned short* bufB = bufA + NF;                     // feat2h (19.2 MB)
    float* h       = (float*)(bufB + NF);                 // fp32 [N_NODES,64] (38.4 MB)
    // rows2/pv overlay h (both dead before the first spmm writes h)
    int*   rows2   = (int*)h;                             // 9.6 MB
    int2*  pv      = (int2*)(rows2 + NNZ);                // 19.2 MB
    int2*  packed  = (int2*)(h + NF);                     // 19.2 MB
    int*   row_ptr = (int*)(packed + NNZ);                // N_NODES+1
    int*   cnt     = row_ptr + (N_NODES + 1);             // N_NODES
    int*   bsums   = cnt + N_NODES;                       // 1024
    int*   boffs   = bsums + 1024;                        // NBUCK
    // E/H1 overlay h (h dead after second gemm64)
    unsigned short* E  = (unsigned short*)h;              // [BATCH,384] bf16 (12.6 MB)
    float* H1 = (float*)(E + (size_t)BATCH * D_CAT);      // [BATCH,64] fp32

    const int SCAN_NB   = (N_NODES + 1023) / 1024;        // 147
    const int edge_grid = (NNZ + 255) / 256;              // 9375
    const int spmm_grid = (N_NODES + 3) / 4;              // 37500
    const int gemm_grid = (N_NODES + 63) / 64;            // 2344
    const int cvt_grid  = (int)((NF / 4 + 255) / 256);    // 9375

    // ---- Build CSR via two-level counting sort (shared by both layers)
    hipMemsetAsync(cnt, 0, N_NODES * sizeof(int), stream);
    hist_rows<<<edge_grid, 256, 0, stream>>>(lap_rows, cnt, NNZ);
    scan1<<<SCAN_NB, 1024, 0, stream>>>(cnt, row_ptr, bsums, N_NODES);
    scan2<<<1, 1024, 0, stream>>>(bsums, SCAN_NB);
    scan3<<<SCAN_NB, 1024, 0, stream>>>(row_ptr, boffs, bsums, N_NODES, NNZ);
    coarse_bin<<<edge_grid, 256, 0, stream>>>(lap_rows, lap_cols, lap_vals,
                                              boffs, rows2, pv, NNZ);
    fine_scatter<<<NBUCK, 256, 0, stream>>>(row_ptr, rows2, pv, packed);

    // ---- feat0h = bf16(concat(uEmb, iEmb))
    cvt_feat0<<<cvt_grid, 256, 0, stream>>>((const float4*)uEmb, NUM_USERS * EMB / 4,
                                            (const float4*)iEmb, NUM_ITEMS * EMB / 4,
                                            (ushort4*)bufA);

    // ---- Layer 1: h = (L+I)@feat0 ; feat1h = bf16(relu(h@gW0+gb0))
    spmm_csr<<<spmm_grid, 256, 0, stream>>>(row_ptr, packed, (const unsigned int*)bufA,
                                            (float2*)h, N_NODES);
    gemm64_relu_bf16<<<gemm_grid, 256, 0, stream>>>(h, gW0, gb0, bufA, N_NODES);

    // ---- Layer 2: h = (L+I)@feat1 ; feat2h = bf16(relu(h@gW1+gb1))
    spmm_csr<<<spmm_grid, 256, 0, stream>>>(row_ptr, packed, (const unsigned int*)bufA,
                                            (float2*)h, N_NODES);
    gemm64_relu_bf16<<<gemm_grid, 256, 0, stream>>>(h, gW1, gb1, bufB, N_NODES);

    // ---- Gather per-sample concatenated features (E overlays h)
    gather_e<<<BATCH, 384, 0, stream>>>(userIdx, itemIdx, uEmb, iEmb, bufA, bufB, E);

    // ---- MLP
    gemm384_bf16_relu<<<(BATCH + 63) / 64, 256, 0, stream>>>(E, W1, b1, H1, BATCH);
    mlp23<<<512, 256, 0, stream>>>(H1, W2, b2, W3, b3, out);
}

// Round 7
// 777.197 us; speedup vs baseline: 1.0913x; 1.0913x over previous
//
#include <hip/hip_runtime.h>
#include <hip/hip_bf16.h>

// Problem constants (from reference)
#define NUM_USERS 100000
#define NUM_ITEMS 50000
#define N_NODES   150000   // NUM_USERS + NUM_ITEMS
#define EMB       64
#define NNZ       2400000
#define BATCH     16384
#define D_CAT     384      // EMB*3*2
#define BSHIFT    5        // 32 rows per bucket
#define NBUCK     ((N_NODES + 31) >> 5)   // 4688
#define EPB       8192     // edges per multisplit block

// ---- bf16 helpers (bit-level, RN-even for f32->bf16) -----------------------
__device__ __forceinline__ unsigned short f2bf(float f) {
    unsigned u = __float_as_uint(f);
    unsigned r = u + 0x7fffu + ((u >> 16) & 1u);
    return (unsigned short)(r >> 16);
}
__device__ __forceinline__ float bflo(unsigned u) { return __uint_as_float(u << 16); }
__device__ __forceinline__ float bfhi(unsigned u) { return __uint_as_float(u & 0xffff0000u); }

// ---------------------------------------------------------------------------
// CSR build step 1: histogram of row indices. cnt must be zeroed first.
// ---------------------------------------------------------------------------
__global__ __launch_bounds__(256) void hist_rows(const int* __restrict__ rows,
                                                 int* __restrict__ cnt, int nnz) {
    int i = blockIdx.x * 256 + threadIdx.x;
    if (i < nnz) atomicAdd(&cnt[rows[i]], 1);
}

// ---------------------------------------------------------------------------
// CSR build step 2a: per-block (1024-elem) exclusive scan of cnt -> partial,
// block totals -> blockSums. partial stored into row_ptr (temporarily).
// ---------------------------------------------------------------------------
__global__ __launch_bounds__(1024) void scan1(const int* __restrict__ cnt,
                                              int* __restrict__ partial,
                                              int* __restrict__ blockSums, int n) {
    __shared__ int s[1024];
    int t = threadIdx.x;
    int i = blockIdx.x * 1024 + t;
    int x = (i < n) ? cnt[i] : 0;
    s[t] = x;
    __syncthreads();
#pragma unroll
    for (int off = 1; off < 1024; off <<= 1) {
        int v = (t >= off) ? s[t - off] : 0;
        __syncthreads();
        s[t] += v;
        __syncthreads();
    }
    if (i < n) partial[i] = s[t] - x;          // exclusive within block
    if (t == 1023) blockSums[blockIdx.x] = s[t];
}

// ---------------------------------------------------------------------------
// CSR build step 2b: single-block exclusive scan of blockSums (in place).
// ---------------------------------------------------------------------------
__global__ __launch_bounds__(1024) void scan2(int* __restrict__ blockSums, int nb) {
    __shared__ int s[1024];
    int t = threadIdx.x;
    int x = (t < nb) ? blockSums[t] : 0;
    s[t] = x;
    __syncthreads();
#pragma unroll
    for (int off = 1; off < 1024; off <<= 1) {
        int v = (t >= off) ? s[t - off] : 0;
        __syncthreads();
        s[t] += v;
        __syncthreads();
    }
    if (t < nb) blockSums[t] = s[t] - x;       // exclusive
}

// ---------------------------------------------------------------------------
// CSR build step 2c: row_ptr[i] = partial[i] + blockOffs[blk]. Also emits the
// bucket-granular tail pointers boffs[b] = row_ptr[b*32], and row_ptr[n]=nnz.
// ---------------------------------------------------------------------------
__global__ __launch_bounds__(1024) void scan3(int* __restrict__ row_ptr,
                                              int* __restrict__ boffs,
                                              const int* __restrict__ blockSums,
                                              int n, int nnz) {
    int t = threadIdx.x;
    int i = blockIdx.x * 1024 + t;
    if (i < n) {
        int v = row_ptr[i] + blockSums[blockIdx.x];
        row_ptr[i] = v;
        if ((i & 31) == 0) boffs[i >> BSHIFT] = v;
    }
    if (i == 0) row_ptr[n] = nnz;
}

// ---------------------------------------------------------------------------
// Pass B: LDS-staged multisplit into 32-row buckets.
// Round-6 lesson: global-atomic tail scatter gives every 64B line ~5 distinct
// XCD writers -> no combining, 192 MB writeback. Here each block (a) builds an
// LDS histogram of its 8192 edges, (b) reserves a contiguous range per bucket
// with ONE global atomic, (c) scatters into its own ranges -> every output
// line has a single CU writer (~1x write amplification).
// pv payload: .x = (r_local<<18) | col   (col < 2^18, r_local < 32), .y = val
// ---------------------------------------------------------------------------
__global__ __launch_bounds__(1024) void coarse_multisplit(const int* __restrict__ rows,
                                                          const int* __restrict__ cols,
                                                          const float* __restrict__ vals,
                                                          int* __restrict__ gtails,
                                                          int2* __restrict__ pv, int nnz) {
    __shared__ int hcnt[NBUCK];
    int tid = threadIdx.x;
    int e0 = blockIdx.x * EPB;
    int e1 = e0 + EPB < nnz ? e0 + EPB : nnz;

    for (int i = tid; i < NBUCK; i += 1024) hcnt[i] = 0;
    __syncthreads();
    for (int i = e0 + tid; i < e1; i += 1024)
        atomicAdd(&hcnt[rows[i] >> BSHIFT], 1);
    __syncthreads();
    for (int i = tid; i < NBUCK; i += 1024) {
        int c = hcnt[i];
        if (c) hcnt[i] = atomicAdd(&gtails[i], c);   // global base for this block
    }
    __syncthreads();
    for (int i = e0 + tid; i < e1; i += 1024) {
        int r = rows[i];
        int pos = atomicAdd(&hcnt[r >> BSHIFT], 1);  // LDS bump from global base
        pv[pos] = make_int2(((r & 31) << 18) | cols[i], __float_as_int(vals[i]));
    }
}

// ---------------------------------------------------------------------------
// Pass C: fine scatter within a bucket. One block per bucket; fine counters
// in LDS; output window written by this CU only.
// ---------------------------------------------------------------------------
__global__ __launch_bounds__(256) void fine_scatter(const int* __restrict__ row_ptr,
                                                    const int2* __restrict__ pv,
                                                    int2* __restrict__ packed) {
    __shared__ int loff[33];
    int b = blockIdx.x;
    int r0 = b << BSHIFT;
    int nr = N_NODES - r0 < 32 ? N_NODES - r0 : 32;
    int tid = threadIdx.x;
    if (tid <= 32) {
        int rr = r0 + tid;
        loff[tid] = row_ptr[rr > N_NODES ? N_NODES : rr];
    }
    __syncthreads();
    int lo = loff[0];
    int hi = loff[nr];
    for (int i = lo + tid; i < hi; i += 256) {
        int2 e = pv[i];
        int rl = e.x >> 18;
        int col = e.x & 0x3FFFF;
        int pos = atomicAdd(&loff[rl], 1);
        packed[pos] = make_int2(col, e.y);
    }
}

// ---------------------------------------------------------------------------
// Convert concat(uEmb,iEmb) fp32 -> bf16 table (4 elems / thread)
// ---------------------------------------------------------------------------
__global__ __launch_bounds__(256) void cvt_feat0(const float4* __restrict__ a, int na4,
                                                 const float4* __restrict__ b, int nb4,
                                                 ushort4* __restrict__ dst) {
    int i = blockIdx.x * 256 + threadIdx.x;
    if (i >= na4 + nb4) return;
    float4 v = (i < na4) ? a[i] : b[i - na4];
    ushort4 o;
    o.x = f2bf(v.x); o.y = f2bf(v.y); o.z = f2bf(v.z); o.w = f2bf(v.w);
    dst[i] = o;
}

// ---------------------------------------------------------------------------
// SPMM (CSR): h[r] = x[r] + sum_edges v * x[c]  (bf16 gathers, fp32 acc).
// One wave per row; half-wave per edge. (Unchanged — proven in rounds 4-6.)
// ---------------------------------------------------------------------------
__global__ __launch_bounds__(256) void spmm_csr(const int* __restrict__ row_ptr,
                                                const int2* __restrict__ packed,
                                                const unsigned int* __restrict__ xh, // bf16x2, stride 32/row
                                                float2* __restrict__ h,              // stride 32/row
                                                int n_rows) {
    int tid = threadIdx.x;
    int lane = tid & 63;
    int wave = tid >> 6;
    int half = lane >> 5;
    int k = lane & 31;
    int r = blockIdx.x * 4 + wave;
    if (r >= n_rows) return;

    unsigned su = xh[(size_t)r * 32 + k];
    float2 acc;
    acc.x = half ? 0.f : bflo(su);
    acc.y = half ? 0.f : bfhi(su);

    int e = row_ptr[r] + half;
    int end = row_ptr[r + 1];
    for (; e + 6 < end; e += 8) {
        int2 p0 = packed[e + 0];
        int2 p1 = packed[e + 2];
        int2 p2 = packed[e + 4];
        int2 p3 = packed[e + 6];
        unsigned x0 = xh[(size_t)p0.x * 32 + k];
        unsigned x1 = xh[(size_t)p1.x * 32 + k];
        unsigned x2 = xh[(size_t)p2.x * 32 + k];
        unsigned x3 = xh[(size_t)p3.x * 32 + k];
        float v0 = __int_as_float(p0.y), v1 = __int_as_float(p1.y);
        float v2 = __int_as_float(p2.y), v3 = __int_as_float(p3.y);
        acc.x = fmaf(v0, bflo(x0), acc.x); acc.y = fmaf(v0, bfhi(x0), acc.y);
        acc.x = fmaf(v1, bflo(x1), acc.x); acc.y = fmaf(v1, bfhi(x1), acc.y);
        acc.x = fmaf(v2, bflo(x2), acc.x); acc.y = fmaf(v2, bfhi(x2), acc.y);
        acc.x = fmaf(v3, bflo(x3), acc.x); acc.y = fmaf(v3, bfhi(x3), acc.y);
    }
    for (; e < end; e += 2) {
        int2 p = packed[e];
        unsigned x = xh[(size_t)p.x * 32 + k];
        float v = __int_as_float(p.y);
        acc.x = fmaf(v, bflo(x), acc.x);
        acc.y = fmaf(v, bfhi(x), acc.y);
    }

    acc.x += __shfl_xor(acc.x, 32, 64);
    acc.y += __shfl_xor(acc.y, 32, 64);
    if (!half) h[(size_t)r * 32 + k] = acc;
}

// ---------------------------------------------------------------------------
// out_bf16[r][c] = relu( b[c] + sum_{k<64} X[r][k] * W[k][c] )
// ---------------------------------------------------------------------------
__global__ __launch_bounds__(256) void gemm64_relu_bf16(const float* __restrict__ X,
                                                        const float* __restrict__ W,
                                                        const float* __restrict__ bia,
                                                        unsigned short* __restrict__ outh,
                                                        int n_rows) {
    __shared__ float Wl[64 * 64];
    int tid = threadIdx.x;
    int lane = tid & 63;
    int wave = tid >> 6;
    int r0 = blockIdx.x * 64 + wave * 16;
    int last = n_rows - 1;
    for (int i = tid; i < 64 * 64; i += 256) Wl[i] = W[i];
    __syncthreads();

    const float* rowp[16];
#pragma unroll
    for (int i = 0; i < 16; ++i) {
        int r = r0 + i;
        r = r > last ? last : r;
        rowp[i] = X + (size_t)r * 64;
    }
    float acc[16];
    float bv = bia[lane];
#pragma unroll
    for (int i = 0; i < 16; ++i) acc[i] = bv;

#pragma unroll 1
    for (int k = 0; k < 64; k += 4) {
        float w0 = Wl[(k + 0) * 64 + lane];
        float w1 = Wl[(k + 1) * 64 + lane];
        float w2 = Wl[(k + 2) * 64 + lane];
        float w3 = Wl[(k + 3) * 64 + lane];
#pragma unroll
        for (int i = 0; i < 16; ++i) {
            float4 e = *(const float4*)(rowp[i] + k);
            acc[i] = fmaf(e.x, w0, acc[i]);
            acc[i] = fmaf(e.y, w1, acc[i]);
            acc[i] = fmaf(e.z, w2, acc[i]);
            acc[i] = fmaf(e.w, w3, acc[i]);
        }
    }
#pragma unroll
    for (int i = 0; i < 16; ++i) {
        int r = r0 + i;
        if (r < n_rows) outh[(size_t)r * 64 + lane] = f2bf(fmaxf(acc[i], 0.f));
    }
}

// ---------------------------------------------------------------------------
// Gather concatenated per-sample features -> bf16 E (one 384-thread block/row)
// ---------------------------------------------------------------------------
__global__ __launch_bounds__(384) void gather_e(const int* __restrict__ userIdx,
                                                const int* __restrict__ itemIdx,
                                                const float* __restrict__ uEmb,
                                                const float* __restrict__ iEmb,
                                                const unsigned short* __restrict__ feat1h,
                                                const unsigned short* __restrict__ feat2h,
                                                unsigned short* __restrict__ E) {
    int b = blockIdx.x;
    int j = threadIdx.x;          // 0..383
    int half = j >= 192;
    int jj = half ? (j - 192) : j;
    int seg = jj >> 6;
    int k = jj & 63;
    unsigned short v;
    if (half == 0) {
        int u = userIdx[b];
        if (seg == 0)      v = f2bf(uEmb[(size_t)u * 64 + k]);
        else if (seg == 1) v = feat1h[(size_t)u * 64 + k];
        else               v = feat2h[(size_t)u * 64 + k];
    } else {
        int it = itemIdx[b];
        if (seg == 0)      v = f2bf(iEmb[(size_t)it * 64 + k]);
        else if (seg == 1) v = feat1h[(size_t)(it + NUM_USERS) * 64 + k];
        else               v = feat2h[(size_t)(it + NUM_USERS) * 64 + k];
    }
    E[(size_t)b * D_CAT + j] = v;
}

// ---------------------------------------------------------------------------
// H1[r][c] = relu( b1[c] + sum_{k<384} E[r][k] * W1[k][c] ), E bf16.
// ---------------------------------------------------------------------------
__global__ __launch_bounds__(256) void gemm384_bf16_relu(const unsigned short* __restrict__ E,
                                                         const float* __restrict__ W,
                                                         const float* __restrict__ bia,
                                                         float* __restrict__ H1,
                                                         int n_rows) {
    __shared__ float Wl[128 * 64];   // 32 KB
    int tid = threadIdx.x;
    int lane = tid & 63;
    int wave = tid >> 6;
    int r0 = blockIdx.x * 64 + wave * 16;
    int last = n_rows - 1;

    const unsigned short* rowp[16];
#pragma unroll
    for (int i = 0; i < 16; ++i) {
        int r = r0 + i;
        r = r > last ? last : r;
        rowp[i] = E + (size_t)r * D_CAT;
    }
    float acc[16];
    float bv = bia[lane];
#pragma unroll
    for (int i = 0; i < 16; ++i) acc[i] = bv;

    for (int k0 = 0; k0 < D_CAT; k0 += 128) {
        if (k0) __syncthreads();
        for (int i = tid; i < 128 * 64; i += 256) Wl[i] = W[k0 * 64 + i];
        __syncthreads();
#pragma unroll 1
        for (int k = 0; k < 128; k += 8) {
            float w0 = Wl[(k + 0) * 64 + lane];
            float w1 = Wl[(k + 1) * 64 + lane];
            float w2 = Wl[(k + 2) * 64 + lane];
            float w3 = Wl[(k + 3) * 64 + lane];
            float w4 = Wl[(k + 4) * 64 + lane];
            float w5 = Wl[(k + 5) * 64 + lane];
            float w6 = Wl[(k + 6) * 64 + lane];
            float w7 = Wl[(k + 7) * 64 + lane];
#pragma unroll
            for (int i = 0; i < 16; ++i) {
                uint4 q = *(const uint4*)(rowp[i] + k0 + k);
                acc[i] = fmaf(bflo(q.x), w0, acc[i]);
                acc[i] = fmaf(bfhi(q.x), w1, acc[i]);
                acc[i] = fmaf(bflo(q.y), w2, acc[i]);
                acc[i] = fmaf(bfhi(q.y), w3, acc[i]);
                acc[i] = fmaf(bflo(q.z), w4, acc[i]);
                acc[i] = fmaf(bfhi(q.z), w5, acc[i]);
                acc[i] = fmaf(bflo(q.w), w6, acc[i]);
                acc[i] = fmaf(bfhi(q.w), w7, acc[i]);
            }
        }
    }
#pragma unroll
    for (int i = 0; i < 16; ++i) {
        int r = r0 + i;
        if (r < n_rows) H1[(size_t)r * 64 + lane] = fmaxf(acc[i], 0.f);
    }
}

// ---------------------------------------------------------------------------
// Fused last two layers: z = H1@W2 + b2 (no relu); out = z@W3 + b3
// ---------------------------------------------------------------------------
__global__ __launch_bounds__(256) void mlp23(const float* __restrict__ H1,
                                             const float* __restrict__ W2,
                                             const float* __restrict__ b2,
                                             const float* __restrict__ W3,
                                             const float* __restrict__ b3,
                                             float* __restrict__ out) {
    __shared__ float Wl[64 * 32];
    __shared__ float w3l[32];
    __shared__ float b2l[32];
    int tid = threadIdx.x;
    for (int i = tid; i < 64 * 32; i += 256) Wl[i] = W2[i];
    if (tid < 32) { w3l[tid] = W3[tid]; b2l[tid] = b2[tid]; }
    __syncthreads();

    int lane = tid & 63;
    int wave = tid >> 6;
    int half = lane >> 5;
    int k = lane & 31;
    int gpair = blockIdx.x * 4 + wave;
    int npairs = gridDim.x * 4;
    float b3v = b3[0];
    for (int p = gpair; p * 2 < BATCH; p += npairs) {
        int r = p * 2 + half;
        float acc = b2l[k];
#pragma unroll
        for (int j = 0; j < 64; ++j)
            acc += H1[(size_t)r * 64 + j] * Wl[j * 32 + k];
        acc = acc * w3l[k];
#pragma unroll
        for (int off = 16; off; off >>= 1)
            acc += __shfl_xor(acc, off, 64);
        if (k == 0) out[r] = acc + b3v;
    }
}

// ---------------------------------------------------------------------------
extern "C" void kernel_launch(void* const* d_in, const int* in_sizes, int n_in,
                              void* d_out, int out_size, void* d_ws, size_t ws_size,
                              hipStream_t stream) {
    const int*   userIdx = (const int*)  d_in[0];
    const int*   itemIdx = (const int*)  d_in[1];
    const int*   lap_rows= (const int*)  d_in[2];
    const int*   lap_cols= (const int*)  d_in[3];
    const float* lap_vals= (const float*)d_in[4];
    const float* uEmb    = (const float*)d_in[5];
    const float* iEmb    = (const float*)d_in[6];
    const float* gW0     = (const float*)d_in[7];
    const float* gb0     = (const float*)d_in[8];
    const float* gW1     = (const float*)d_in[9];
    const float* gb1     = (const float*)d_in[10];
    const float* W1      = (const float*)d_in[11];
    const float* b1      = (const float*)d_in[12];
    const float* W2      = (const float*)d_in[13];
    const float* b2      = (const float*)d_in[14];
    const float* W3      = (const float*)d_in[15];
    const float* b3      = (const float*)d_in[16];
    float* out = (float*)d_out;

    const size_t NF = (size_t)N_NODES * EMB;              // 9.6M elements
    char* w = (char*)d_ws;
    unsigned short* bufA = (unsigned short*)w;            // feat0h/feat1h (19.2 MB)
    unsigned short* bufB = bufA + NF;                     // feat2h (19.2 MB)
    float* h       = (float*)(bufB + NF);                 // fp32 [N_NODES,64] (38.4 MB)
    // pv overlays h (dead before the first spmm writes h)
    int2*  pv      = (int2*)h;                            // 19.2 MB
    int2*  packed  = (int2*)(h + NF);                     // 19.2 MB
    int*   row_ptr = (int*)(packed + NNZ);                // N_NODES+1
    int*   cnt     = row_ptr + (N_NODES + 1);             // N_NODES
    int*   bsums   = cnt + N_NODES;                       // 1024
    int*   boffs   = bsums + 1024;                        // NBUCK (mutable tails)
    // E/H1 overlay h (h dead after second gemm64)
    unsigned short* E  = (unsigned short*)h;              // [BATCH,384] bf16 (12.6 MB)
    float* H1 = (float*)(E + (size_t)BATCH * D_CAT);      // [BATCH,64] fp32

    const int SCAN_NB   = (N_NODES + 1023) / 1024;        // 147
    const int edge_grid = (NNZ + 255) / 256;              // 9375
    const int ms_grid   = (NNZ + EPB - 1) / EPB;          // 293
    const int spmm_grid = (N_NODES + 3) / 4;              // 37500
    const int gemm_grid = (N_NODES + 63) / 64;            // 2344
    const int cvt_grid  = (int)((NF / 4 + 255) / 256);    // 9375

    // ---- Build CSR via LDS-multisplit counting sort (shared by both layers)
    hipMemsetAsync(cnt, 0, N_NODES * sizeof(int), stream);
    hist_rows<<<edge_grid, 256, 0, stream>>>(lap_rows, cnt, NNZ);
    scan1<<<SCAN_NB, 1024, 0, stream>>>(cnt, row_ptr, bsums, N_NODES);
    scan2<<<1, 1024, 0, stream>>>(bsums, SCAN_NB);
    scan3<<<SCAN_NB, 1024, 0, stream>>>(row_ptr, boffs, bsums, N_NODES, NNZ);
    coarse_multisplit<<<ms_grid, 1024, 0, stream>>>(lap_rows, lap_cols, lap_vals,
                                                    boffs, pv, NNZ);
    fine_scatter<<<NBUCK, 256, 0, stream>>>(row_ptr, pv, packed);

    // ---- feat0h = bf16(concat(uEmb, iEmb))
    cvt_feat0<<<cvt_grid, 256, 0, stream>>>((const float4*)uEmb, NUM_USERS * EMB / 4,
                                            (const float4*)iEmb, NUM_ITEMS * EMB / 4,
                                            (ushort4*)bufA);

    // ---- Layer 1: h = (L+I)@feat0 ; feat1h = bf16(relu(h@gW0+gb0))
    spmm_csr<<<spmm_grid, 256, 0, stream>>>(row_ptr, packed, (const unsigned int*)bufA,
                                            (float2*)h, N_NODES);
    gemm64_relu_bf16<<<gemm_grid, 256, 0, stream>>>(h, gW0, gb0, bufA, N_NODES);

    // ---- Layer 2: h = (L+I)@feat1 ; feat2h = bf16(relu(h@gW1+gb1))
    spmm_csr<<<spmm_grid, 256, 0, stream>>>(row_ptr, packed, (const unsigned int*)bufA,
                                            (float2*)h, N_NODES);
    gemm64_relu_bf16<<<gemm_grid, 256, 0, stream>>>(h, gW1, gb1, bufB, N_NODES);

    // ---- Gather per-sample concatenated features (E overlays h)
    gather_e<<<BATCH, 384, 0, stream>>>(userIdx, itemIdx, uEmb, iEmb, bufA, bufB, E);

    // ---- MLP
    gemm384_bf16_relu<<<(BATCH + 63) / 64, 256, 0, stream>>>(E, W1, b1, H1, BATCH);
    mlp23<<<512, 256, 0, stream>>>(H1, W2, b2, W3, b3, out);
}

// Round 8
// 668.524 us; speedup vs baseline: 1.2687x; 1.1626x over previous
//
#include <hip/hip_runtime.h>
#include <hip/hip_bf16.h>

// Problem constants (from reference)
#define NUM_USERS 100000
#define NUM_ITEMS 50000
#define N_NODES   150000   // NUM_USERS + NUM_ITEMS
#define EMB       64
#define NNZ       2400000
#define BATCH     16384
#define D_CAT     384      // EMB*3*2
#define BSHIFT    5        // 32 rows per bucket
#define NBUCK     ((N_NODES + 31) >> 5)   // 4688
#define EPB       8192     // edges per multisplit block

// ---- bf16 helpers (bit-level, RN-even for f32->bf16) -----------------------
__device__ __forceinline__ unsigned short f2bf(float f) {
    unsigned u = __float_as_uint(f);
    unsigned r = u + 0x7fffu + ((u >> 16) & 1u);
    return (unsigned short)(r >> 16);
}
__device__ __forceinline__ float bflo(unsigned u) { return __uint_as_float(u << 16); }
__device__ __forceinline__ float bfhi(unsigned u) { return __uint_as_float(u & 0xffff0000u); }

// ---------------------------------------------------------------------------
// CSR build step 1: histogram of row indices. cnt must be zeroed first.
// ---------------------------------------------------------------------------
__global__ __launch_bounds__(256) void hist_rows(const int* __restrict__ rows,
                                                 int* __restrict__ cnt, int nnz) {
    int i = blockIdx.x * 256 + threadIdx.x;
    if (i < nnz) atomicAdd(&cnt[rows[i]], 1);
}

// ---------------------------------------------------------------------------
// CSR build step 2a: per-block (1024-elem) exclusive scan of cnt -> partial,
// block totals -> blockSums. partial stored into row_ptr (temporarily).
// ---------------------------------------------------------------------------
__global__ __launch_bounds__(1024) void scan1(const int* __restrict__ cnt,
                                              int* __restrict__ partial,
                                              int* __restrict__ blockSums, int n) {
    __shared__ int s[1024];
    int t = threadIdx.x;
    int i = blockIdx.x * 1024 + t;
    int x = (i < n) ? cnt[i] : 0;
    s[t] = x;
    __syncthreads();
#pragma unroll
    for (int off = 1; off < 1024; off <<= 1) {
        int v = (t >= off) ? s[t - off] : 0;
        __syncthreads();
        s[t] += v;
        __syncthreads();
    }
    if (i < n) partial[i] = s[t] - x;          // exclusive within block
    if (t == 1023) blockSums[blockIdx.x] = s[t];
}

// ---------------------------------------------------------------------------
// CSR build step 2b: single-block exclusive scan of blockSums (in place).
// ---------------------------------------------------------------------------
__global__ __launch_bounds__(1024) void scan2(int* __restrict__ blockSums, int nb) {
    __shared__ int s[1024];
    int t = threadIdx.x;
    int x = (t < nb) ? blockSums[t] : 0;
    s[t] = x;
    __syncthreads();
#pragma unroll
    for (int off = 1; off < 1024; off <<= 1) {
        int v = (t >= off) ? s[t - off] : 0;
        __syncthreads();
        s[t] += v;
        __syncthreads();
    }
    if (t < nb) blockSums[t] = s[t] - x;       // exclusive
}

// ---------------------------------------------------------------------------
// CSR build step 2c: row_ptr[i] = partial[i] + blockOffs[blk]. Also emits the
// bucket-granular tail pointers boffs[b] = row_ptr[b*32], and row_ptr[n]=nnz.
// ---------------------------------------------------------------------------
__global__ __launch_bounds__(1024) void scan3(int* __restrict__ row_ptr,
                                              int* __restrict__ boffs,
                                              const int* __restrict__ blockSums,
                                              int n, int nnz) {
    int t = threadIdx.x;
    int i = blockIdx.x * 1024 + t;
    if (i < n) {
        int v = row_ptr[i] + blockSums[blockIdx.x];
        row_ptr[i] = v;
        if ((i & 31) == 0) boffs[i >> BSHIFT] = v;
    }
    if (i == 0) row_ptr[n] = nnz;
}

// ---------------------------------------------------------------------------
// Pass B: LDS-staged multisplit into 32-row buckets (single-CU line writers).
// pv payload: .x = (r_local<<18) | col, .y = val
// ---------------------------------------------------------------------------
__global__ __launch_bounds__(1024) void coarse_multisplit(const int* __restrict__ rows,
                                                          const int* __restrict__ cols,
                                                          const float* __restrict__ vals,
                                                          int* __restrict__ gtails,
                                                          int2* __restrict__ pv, int nnz) {
    __shared__ int hcnt[NBUCK];
    int tid = threadIdx.x;
    int e0 = blockIdx.x * EPB;
    int e1 = e0 + EPB < nnz ? e0 + EPB : nnz;

    for (int i = tid; i < NBUCK; i += 1024) hcnt[i] = 0;
    __syncthreads();
    for (int i = e0 + tid; i < e1; i += 1024)
        atomicAdd(&hcnt[rows[i] >> BSHIFT], 1);
    __syncthreads();
    for (int i = tid; i < NBUCK; i += 1024) {
        int c = hcnt[i];
        if (c) hcnt[i] = atomicAdd(&gtails[i], c);   // global base for this block
    }
    __syncthreads();
    for (int i = e0 + tid; i < e1; i += 1024) {
        int r = rows[i];
        int pos = atomicAdd(&hcnt[r >> BSHIFT], 1);  // LDS bump from global base
        pv[pos] = make_int2(((r & 31) << 18) | cols[i], __float_as_int(vals[i]));
    }
}

// ---------------------------------------------------------------------------
// Pass C: fine scatter within a bucket (LDS counters, single-CU window).
// ---------------------------------------------------------------------------
__global__ __launch_bounds__(256) void fine_scatter(const int* __restrict__ row_ptr,
                                                    const int2* __restrict__ pv,
                                                    int2* __restrict__ packed) {
    __shared__ int loff[33];
    int b = blockIdx.x;
    int r0 = b << BSHIFT;
    int nr = N_NODES - r0 < 32 ? N_NODES - r0 : 32;
    int tid = threadIdx.x;
    if (tid <= 32) {
        int rr = r0 + tid;
        loff[tid] = row_ptr[rr > N_NODES ? N_NODES : rr];
    }
    __syncthreads();
    int lo = loff[0];
    int hi = loff[nr];
    for (int i = lo + tid; i < hi; i += 256) {
        int2 e = pv[i];
        int rl = e.x >> 18;
        int col = e.x & 0x3FFFF;
        int pos = atomicAdd(&loff[rl], 1);
        packed[pos] = make_int2(col, e.y);
    }
}

// ---------------------------------------------------------------------------
// Convert concat(uEmb,iEmb) fp32 -> bf16 table (4 elems / thread)
// ---------------------------------------------------------------------------
__global__ __launch_bounds__(256) void cvt_feat0(const float4* __restrict__ a, int na4,
                                                 const float4* __restrict__ b, int nb4,
                                                 ushort4* __restrict__ dst) {
    int i = blockIdx.x * 256 + threadIdx.x;
    if (i >= na4 + nb4) return;
    float4 v = (i < na4) ? a[i] : b[i - na4];
    ushort4 o;
    o.x = f2bf(v.x); o.y = f2bf(v.y); o.z = f2bf(v.z); o.w = f2bf(v.w);
    dst[i] = o;
}

// ---------------------------------------------------------------------------
// Z = X @ W   (X: bf16 table [n x 64], W: fp32 [64 x 64], Z: bf16 [n x 64])
// Exploits ((L+I)X)W == (L+I)(XW): GEMM runs on the contiguous table BEFORE
// the spmm, so the fp32 h intermediate disappears. All inner-loop reads are
// LDS (round-7 gemm64 was latency-bound on wave-uniform global broadcasts:
// 104 us at 370 GB/s, VALUBusy 27%).
// Block: 256 thr, 64 rows; wave = 16 rows, lane = output col.
// ---------------------------------------------------------------------------
__global__ __launch_bounds__(256) void gemm_table_bf16(const unsigned* __restrict__ Xh,
                                                       const float* __restrict__ W,
                                                       unsigned short* __restrict__ Zh,
                                                       int n_rows) {
    __shared__ float Wl[64 * 64];        // 16 KB
    __shared__ uint4 Xl4[64 * 8];        // 8 KB: 64 rows x 32 uints (bf16x2)
    int tid = threadIdx.x;
    int lane = tid & 63;
    int wave = tid >> 6;
    int r0 = blockIdx.x * 64;
    int nr = n_rows - r0; if (nr > 64) nr = 64;

    for (int i = tid; i < 64 * 64; i += 256) Wl[i] = W[i];
    const uint4* Xg4 = (const uint4*)(Xh + (size_t)r0 * 32);
    for (int i = tid; i < nr * 8; i += 256) Xl4[i] = Xg4[i];
    __syncthreads();

    const unsigned* Xl = (const unsigned*)Xl4;
    int rbase = wave * 16;
    float acc[16];
#pragma unroll
    for (int i = 0; i < 16; ++i) acc[i] = 0.f;

#pragma unroll 1
    for (int kc = 0; kc < 8; ++kc) {     // 8 k-values per chunk
        float w0 = Wl[(kc * 8 + 0) * 64 + lane];
        float w1 = Wl[(kc * 8 + 1) * 64 + lane];
        float w2 = Wl[(kc * 8 + 2) * 64 + lane];
        float w3 = Wl[(kc * 8 + 3) * 64 + lane];
        float w4 = Wl[(kc * 8 + 4) * 64 + lane];
        float w5 = Wl[(kc * 8 + 5) * 64 + lane];
        float w6 = Wl[(kc * 8 + 6) * 64 + lane];
        float w7 = Wl[(kc * 8 + 7) * 64 + lane];
#pragma unroll
        for (int i = 0; i < 16; ++i) {
            uint4 q = *(const uint4*)&Xl[(rbase + i) * 32 + kc * 4];  // broadcast
            acc[i] = fmaf(bflo(q.x), w0, acc[i]);
            acc[i] = fmaf(bfhi(q.x), w1, acc[i]);
            acc[i] = fmaf(bflo(q.y), w2, acc[i]);
            acc[i] = fmaf(bfhi(q.y), w3, acc[i]);
            acc[i] = fmaf(bflo(q.z), w4, acc[i]);
            acc[i] = fmaf(bfhi(q.z), w5, acc[i]);
            acc[i] = fmaf(bflo(q.w), w6, acc[i]);
            acc[i] = fmaf(bfhi(q.w), w7, acc[i]);
        }
    }
#pragma unroll
    for (int i = 0; i < 16; ++i) {
        int r = r0 + rbase + i;
        if (r < n_rows) Zh[(size_t)r * 64 + lane] = f2bf(acc[i]);
    }
}

// ---------------------------------------------------------------------------
// SPMM + bias + relu: out[r] = relu( Z[r] + sum_edges v * Z[c] + bias ), bf16.
// One wave per row; half-wave per edge; bf16x2 per lane (proven structure).
// ---------------------------------------------------------------------------
__global__ __launch_bounds__(256) void spmm_bias_relu(const int* __restrict__ row_ptr,
                                                      const int2* __restrict__ packed,
                                                      const unsigned* __restrict__ zh,  // bf16x2, 32/row
                                                      const float* __restrict__ bias,   // [64] fp32
                                                      unsigned* __restrict__ outh,      // bf16x2, 32/row
                                                      int n_rows) {
    int tid = threadIdx.x;
    int lane = tid & 63;
    int wave = tid >> 6;
    int half = lane >> 5;
    int k = lane & 31;
    int r = blockIdx.x * 4 + wave;
    if (r >= n_rows) return;

    unsigned su = zh[(size_t)r * 32 + k];
    float2 acc;
    acc.x = half ? 0.f : bflo(su);
    acc.y = half ? 0.f : bfhi(su);

    int e = row_ptr[r] + half;
    int end = row_ptr[r + 1];
    for (; e + 6 < end; e += 8) {
        int2 p0 = packed[e + 0];
        int2 p1 = packed[e + 2];
        int2 p2 = packed[e + 4];
        int2 p3 = packed[e + 6];
        unsigned x0 = zh[(size_t)p0.x * 32 + k];
        unsigned x1 = zh[(size_t)p1.x * 32 + k];
        unsigned x2 = zh[(size_t)p2.x * 32 + k];
        unsigned x3 = zh[(size_t)p3.x * 32 + k];
        float v0 = __int_as_float(p0.y), v1 = __int_as_float(p1.y);
        float v2 = __int_as_float(p2.y), v3 = __int_as_float(p3.y);
        acc.x = fmaf(v0, bflo(x0), acc.x); acc.y = fmaf(v0, bfhi(x0), acc.y);
        acc.x = fmaf(v1, bflo(x1), acc.x); acc.y = fmaf(v1, bfhi(x1), acc.y);
        acc.x = fmaf(v2, bflo(x2), acc.x); acc.y = fmaf(v2, bfhi(x2), acc.y);
        acc.x = fmaf(v3, bflo(x3), acc.x); acc.y = fmaf(v3, bfhi(x3), acc.y);
    }
    for (; e < end; e += 2) {
        int2 p = packed[e];
        unsigned x = zh[(size_t)p.x * 32 + k];
        float v = __int_as_float(p.y);
        acc.x = fmaf(v, bflo(x), acc.x);
        acc.y = fmaf(v, bfhi(x), acc.y);
    }

    acc.x += __shfl_xor(acc.x, 32, 64);
    acc.y += __shfl_xor(acc.y, 32, 64);
    if (!half) {
        float2 bv = *(const float2*)(bias + 2 * k);
        float ox = fmaxf(acc.x + bv.x, 0.f);
        float oy = fmaxf(acc.y + bv.y, 0.f);
        outh[(size_t)r * 32 + k] = ((unsigned)f2bf(oy) << 16) | (unsigned)f2bf(ox);
    }
}

// ---------------------------------------------------------------------------
// Gather concatenated per-sample features -> bf16 E (one 384-thread block/row)
// ---------------------------------------------------------------------------
__global__ __launch_bounds__(384) void gather_e(const int* __restrict__ userIdx,
                                                const int* __restrict__ itemIdx,
                                                const float* __restrict__ uEmb,
                                                const float* __restrict__ iEmb,
                                                const unsigned short* __restrict__ feat1h,
                                                const unsigned short* __restrict__ feat2h,
                                                unsigned short* __restrict__ E) {
    int b = blockIdx.x;
    int j = threadIdx.x;          // 0..383
    int half = j >= 192;
    int jj = half ? (j - 192) : j;
    int seg = jj >> 6;
    int k = jj & 63;
    unsigned short v;
    if (half == 0) {
        int u = userIdx[b];
        if (seg == 0)      v = f2bf(uEmb[(size_t)u * 64 + k]);
        else if (seg == 1) v = feat1h[(size_t)u * 64 + k];
        else               v = feat2h[(size_t)u * 64 + k];
    } else {
        int it = itemIdx[b];
        if (seg == 0)      v = f2bf(iEmb[(size_t)it * 64 + k]);
        else if (seg == 1) v = feat1h[(size_t)(it + NUM_USERS) * 64 + k];
        else               v = feat2h[(size_t)(it + NUM_USERS) * 64 + k];
    }
    E[(size_t)b * D_CAT + j] = v;
}

// ---------------------------------------------------------------------------
// H1[r][c] = relu( b1[c] + sum_{k<384} E[r][k] * W1[k][c] ), E bf16.
// ---------------------------------------------------------------------------
__global__ __launch_bounds__(256) void gemm384_bf16_relu(const unsigned short* __restrict__ E,
                                                         const float* __restrict__ W,
                                                         const float* __restrict__ bia,
                                                         float* __restrict__ H1,
                                                         int n_rows) {
    __shared__ float Wl[128 * 64];   // 32 KB
    int tid = threadIdx.x;
    int lane = tid & 63;
    int wave = tid >> 6;
    int r0 = blockIdx.x * 64 + wave * 16;
    int last = n_rows - 1;

    const unsigned short* rowp[16];
#pragma unroll
    for (int i = 0; i < 16; ++i) {
        int r = r0 + i;
        r = r > last ? last : r;
        rowp[i] = E + (size_t)r * D_CAT;
    }
    float acc[16];
    float bv = bia[lane];
#pragma unroll
    for (int i = 0; i < 16; ++i) acc[i] = bv;

    for (int k0 = 0; k0 < D_CAT; k0 += 128) {
        if (k0) __syncthreads();
        for (int i = tid; i < 128 * 64; i += 256) Wl[i] = W[k0 * 64 + i];
        __syncthreads();
#pragma unroll 1
        for (int k = 0; k < 128; k += 8) {
            float w0 = Wl[(k + 0) * 64 + lane];
            float w1 = Wl[(k + 1) * 64 + lane];
            float w2 = Wl[(k + 2) * 64 + lane];
            float w3 = Wl[(k + 3) * 64 + lane];
            float w4 = Wl[(k + 4) * 64 + lane];
            float w5 = Wl[(k + 5) * 64 + lane];
            float w6 = Wl[(k + 6) * 64 + lane];
            float w7 = Wl[(k + 7) * 64 + lane];
#pragma unroll
            for (int i = 0; i < 16; ++i) {
                uint4 q = *(const uint4*)(rowp[i] + k0 + k);
                acc[i] = fmaf(bflo(q.x), w0, acc[i]);
                acc[i] = fmaf(bfhi(q.x), w1, acc[i]);
                acc[i] = fmaf(bflo(q.y), w2, acc[i]);
                acc[i] = fmaf(bfhi(q.y), w3, acc[i]);
                acc[i] = fmaf(bflo(q.z), w4, acc[i]);
                acc[i] = fmaf(bfhi(q.z), w5, acc[i]);
                acc[i] = fmaf(bflo(q.w), w6, acc[i]);
                acc[i] = fmaf(bfhi(q.w), w7, acc[i]);
            }
        }
    }
#pragma unroll
    for (int i = 0; i < 16; ++i) {
        int r = r0 + i;
        if (r < n_rows) H1[(size_t)r * 64 + lane] = fmaxf(acc[i], 0.f);
    }
}

// ---------------------------------------------------------------------------
// Fused last two layers: z = H1@W2 + b2 (no relu); out = z@W3 + b3
// ---------------------------------------------------------------------------
__global__ __launch_bounds__(256) void mlp23(const float* __restrict__ H1,
                                             const float* __restrict__ W2,
                                             const float* __restrict__ b2,
                                             const float* __restrict__ W3,
                                             const float* __restrict__ b3,
                                             float* __restrict__ out) {
    __shared__ float Wl[64 * 32];
    __shared__ float w3l[32];
    __shared__ float b2l[32];
    int tid = threadIdx.x;
    for (int i = tid; i < 64 * 32; i += 256) Wl[i] = W2[i];
    if (tid < 32) { w3l[tid] = W3[tid]; b2l[tid] = b2[tid]; }
    __syncthreads();

    int lane = tid & 63;
    int wave = tid >> 6;
    int half = lane >> 5;
    int k = lane & 31;
    int gpair = blockIdx.x * 4 + wave;
    int npairs = gridDim.x * 4;
    float b3v = b3[0];
    for (int p = gpair; p * 2 < BATCH; p += npairs) {
        int r = p * 2 + half;
        float acc = b2l[k];
#pragma unroll
        for (int j = 0; j < 64; ++j)
            acc += H1[(size_t)r * 64 + j] * Wl[j * 32 + k];
        acc = acc * w3l[k];
#pragma unroll
        for (int off = 16; off; off >>= 1)
            acc += __shfl_xor(acc, off, 64);
        if (k == 0) out[r] = acc + b3v;
    }
}

// ---------------------------------------------------------------------------
extern "C" void kernel_launch(void* const* d_in, const int* in_sizes, int n_in,
                              void* d_out, int out_size, void* d_ws, size_t ws_size,
                              hipStream_t stream) {
    const int*   userIdx = (const int*)  d_in[0];
    const int*   itemIdx = (const int*)  d_in[1];
    const int*   lap_rows= (const int*)  d_in[2];
    const int*   lap_cols= (const int*)  d_in[3];
    const float* lap_vals= (const float*)d_in[4];
    const float* uEmb    = (const float*)d_in[5];
    const float* iEmb    = (const float*)d_in[6];
    const float* gW0     = (const float*)d_in[7];
    const float* gb0     = (const float*)d_in[8];
    const float* gW1     = (const float*)d_in[9];
    const float* gb1     = (const float*)d_in[10];
    const float* W1      = (const float*)d_in[11];
    const float* b1      = (const float*)d_in[12];
    const float* W2      = (const float*)d_in[13];
    const float* b2      = (const float*)d_in[14];
    const float* W3      = (const float*)d_in[15];
    const float* b3      = (const float*)d_in[16];
    float* out = (float*)d_out;

    const size_t NF = (size_t)N_NODES * EMB;              // 9.6M elements
    char* w = (char*)d_ws;
    unsigned short* bufA = (unsigned short*)w;            // feat0h/feat1h (19.2 MB)
    unsigned short* bufB = bufA + NF;                     // feat2h (19.2 MB)
    char*  region3 = (char*)(bufB + NF);                  // 38.4 MB multi-use
    // region3 uses (all sequential, no overlap in time):
    int2*  pv      = (int2*)region3;                      // CSR build (19.2 MB)
    unsigned short* Zh = (unsigned short*)region3;        // Z table (19.2 MB)
    unsigned short* E  = (unsigned short*)region3;        // [BATCH,384] bf16 (12.6 MB)
    float* H1 = (float*)(E + (size_t)BATCH * D_CAT);      // [BATCH,64] fp32
    int2*  packed  = (int2*)(region3 + NF * sizeof(float)); // 19.2 MB
    int*   row_ptr = (int*)(packed + NNZ);                // N_NODES+1
    int*   cnt     = row_ptr + (N_NODES + 1);             // N_NODES
    int*   bsums   = cnt + N_NODES;                       // 1024
    int*   boffs   = bsums + 1024;                        // NBUCK (mutable tails)

    const int SCAN_NB   = (N_NODES + 1023) / 1024;        // 147
    const int edge_grid = (NNZ + 255) / 256;              // 9375
    const int ms_grid   = (NNZ + EPB - 1) / EPB;          // 293
    const int spmm_grid = (N_NODES + 3) / 4;              // 37500
    const int gemm_grid = (N_NODES + 63) / 64;            // 2344
    const int cvt_grid  = (int)((NF / 4 + 255) / 256);    // 9375

    // ---- Build CSR via LDS-multisplit counting sort (shared by both layers)
    hipMemsetAsync(cnt, 0, N_NODES * sizeof(int), stream);
    hist_rows<<<edge_grid, 256, 0, stream>>>(lap_rows, cnt, NNZ);
    scan1<<<SCAN_NB, 1024, 0, stream>>>(cnt, row_ptr, bsums, N_NODES);
    scan2<<<1, 1024, 0, stream>>>(bsums, SCAN_NB);
    scan3<<<SCAN_NB, 1024, 0, stream>>>(row_ptr, boffs, bsums, N_NODES, NNZ);
    coarse_multisplit<<<ms_grid, 1024, 0, stream>>>(lap_rows, lap_cols, lap_vals,
                                                    boffs, pv, NNZ);
    fine_scatter<<<NBUCK, 256, 0, stream>>>(row_ptr, pv, packed);

    // ---- feat0h = bf16(concat(uEmb, iEmb))
    cvt_feat0<<<cvt_grid, 256, 0, stream>>>((const float4*)uEmb, NUM_USERS * EMB / 4,
                                            (const float4*)iEmb, NUM_ITEMS * EMB / 4,
                                            (ushort4*)bufA);

    // ---- Layer 1 (reordered): Z = feat0@gW0 ; feat1 = relu((L+I)Z + gb0)
    gemm_table_bf16<<<gemm_grid, 256, 0, stream>>>((const unsigned*)bufA, gW0, Zh, N_NODES);
    spmm_bias_relu<<<spmm_grid, 256, 0, stream>>>(row_ptr, packed, (const unsigned*)Zh,
                                                  gb0, (unsigned*)bufA, N_NODES);

    // ---- Layer 2: Z = feat1@gW1 ; feat2 = relu((L+I)Z + gb1)
    gemm_table_bf16<<<gemm_grid, 256, 0, stream>>>((const unsigned*)bufA, gW1, Zh, N_NODES);
    spmm_bias_relu<<<spmm_grid, 256, 0, stream>>>(row_ptr, packed, (const unsigned*)Zh,
                                                  gb1, (unsigned*)bufB, N_NODES);

    // ---- Gather per-sample concatenated features (E overlays region3; Z dead)
    gather_e<<<BATCH, 384, 0, stream>>>(userIdx, itemIdx, uEmb, iEmb, bufA, bufB, E);

    // ---- MLP
    gemm384_bf16_relu<<<(BATCH + 63) / 64, 256, 0, stream>>>(E, W1, b1, H1, BATCH);
    mlp23<<<512, 256, 0, stream>>>(H1, W2, b2, W3, b3, out);
}

// Round 9
// 581.779 us; speedup vs baseline: 1.4578x; 1.1491x over previous
//
#include <hip/hip_runtime.h>
#include <hip/hip_bf16.h>

// Problem constants (from reference)
#define NUM_USERS 100000
#define NUM_ITEMS 50000
#define N_NODES   150000   // NUM_USERS + NUM_ITEMS
#define EMB       64
#define NNZ       2400000
#define BATCH     16384
#define D_CAT     384      // EMB*3*2
#define BSHIFT    5        // 32 rows per bucket
#define NBUCK     ((N_NODES + 31) >> 5)   // 4688
#define EPB       8192     // edges per multisplit block

// ---- bf16 helpers (bit-level, RN-even for f32->bf16) -----------------------
__device__ __forceinline__ unsigned short f2bf(float f) {
    unsigned u = __float_as_uint(f);
    unsigned r = u + 0x7fffu + ((u >> 16) & 1u);
    return (unsigned short)(r >> 16);
}
__device__ __forceinline__ float bflo(unsigned u) { return __uint_as_float(u << 16); }
__device__ __forceinline__ float bfhi(unsigned u) { return __uint_as_float(u & 0xffff0000u); }

// ---------------------------------------------------------------------------
// Bucket histogram, LDS-aggregated. Round-8 lesson: device-scope atomicAdd is
// memory-side (~32 B HBM write each; hist_rows = 2.4M atomics = 74.9 MB).
// Here: LDS histogram per block, ONE global atomic per non-empty bucket per
// block (128 blocks x <=4688 ~ 560K atomics).
// ---------------------------------------------------------------------------
__global__ __launch_bounds__(1024) void bucket_hist(const int* __restrict__ rows,
                                                    int* __restrict__ bcnt, int nnz) {
    __shared__ int h[NBUCK];
    int tid = threadIdx.x;
    for (int i = tid; i < NBUCK; i += 1024) h[i] = 0;
    __syncthreads();
    for (int i = blockIdx.x * 1024 + tid; i < nnz; i += gridDim.x * 1024)
        atomicAdd(&h[rows[i] >> BSHIFT], 1);
    __syncthreads();
    for (int i = tid; i < NBUCK; i += 1024) {
        int c = h[i];
        if (c) atomicAdd(&bcnt[i], c);
    }
}

// ---------------------------------------------------------------------------
// Exclusive scan over the 4688 bucket counts (single block; 5 elems/thread —
// tiny, unlike round-4's 147/thread over 600 KB). Emits boffs (immutable,
// +sentinel) and gtails (mutable copy for the multisplit).
// ---------------------------------------------------------------------------
__global__ __launch_bounds__(1024) void bucket_scan(const int* __restrict__ bcnt,
                                                    int* __restrict__ boffs,
                                                    int* __restrict__ gtails, int nnz) {
    __shared__ int s[1024];
    int t = threadIdx.x;
    const int per = (NBUCK + 1023) / 1024;   // 5
    int lo = t * per, hi = lo + per > NBUCK ? NBUCK : lo + per;
    int loc[5];
    int sum = 0;
    for (int i = lo; i < hi; ++i) { loc[i - lo] = bcnt[i]; sum += loc[i - lo]; }
    s[t] = sum;
    __syncthreads();
#pragma unroll
    for (int off = 1; off < 1024; off <<= 1) {
        int v = (t >= off) ? s[t - off] : 0;
        __syncthreads();
        s[t] += v;
        __syncthreads();
    }
    int run = s[t] - sum;
    for (int i = lo; i < hi; ++i) {
        boffs[i] = run;
        gtails[i] = run;
        run += loc[i - lo];
    }
    if (t == 0) boffs[NBUCK] = nnz;
}

// ---------------------------------------------------------------------------
// Pass B: LDS-staged multisplit into 32-row buckets (single-CU line writers).
// pv payload: .x = (r_local<<18) | col, .y = val
// ---------------------------------------------------------------------------
__global__ __launch_bounds__(1024) void coarse_multisplit(const int* __restrict__ rows,
                                                          const int* __restrict__ cols,
                                                          const float* __restrict__ vals,
                                                          int* __restrict__ gtails,
                                                          int2* __restrict__ pv, int nnz) {
    __shared__ int hcnt[NBUCK];
    int tid = threadIdx.x;
    int e0 = blockIdx.x * EPB;
    int e1 = e0 + EPB < nnz ? e0 + EPB : nnz;

    for (int i = tid; i < NBUCK; i += 1024) hcnt[i] = 0;
    __syncthreads();
    for (int i = e0 + tid; i < e1; i += 1024)
        atomicAdd(&hcnt[rows[i] >> BSHIFT], 1);
    __syncthreads();
    for (int i = tid; i < NBUCK; i += 1024) {
        int c = hcnt[i];
        if (c) hcnt[i] = atomicAdd(&gtails[i], c);   // global base for this block
    }
    __syncthreads();
    for (int i = e0 + tid; i < e1; i += 1024) {
        int r = rows[i];
        int pos = atomicAdd(&hcnt[r >> BSHIFT], 1);  // LDS bump from global base
        pv[pos] = make_int2(((r & 31) << 18) | cols[i], __float_as_int(vals[i]));
    }
}

// ---------------------------------------------------------------------------
// Pass C: fine scatter within a bucket + row_ptr production.
// Counts the bucket's 32 rows from pv in LDS, scans in-block, writes row_ptr
// (coalesced), then scatters. Replaces the global per-row histogram entirely.
// ---------------------------------------------------------------------------
__global__ __launch_bounds__(256) void fine_scatter(const int* __restrict__ boffs,
                                                    const int2* __restrict__ pv,
                                                    int2* __restrict__ packed,
                                                    int* __restrict__ row_ptr, int nnz) {
    __shared__ int rcnt[32];
    __shared__ int loff[32];
    int b = blockIdx.x;
    int tid = threadIdx.x;
    int lo = boffs[b];
    int hi = boffs[b + 1];
    if (tid < 32) rcnt[tid] = 0;
    __syncthreads();
    for (int i = lo + tid; i < hi; i += 256)
        atomicAdd(&rcnt[pv[i].x >> 18], 1);
    __syncthreads();
    if (tid == 0) {
        int run = lo;
#pragma unroll
        for (int j = 0; j < 32; ++j) { loff[j] = run; run += rcnt[j]; }
    }
    __syncthreads();
    int r0 = b << BSHIFT;
    if (tid < 32 && r0 + tid < N_NODES) row_ptr[r0 + tid] = loff[tid];
    if (b == 0 && tid == 0) row_ptr[N_NODES] = nnz;
    __syncthreads();
    for (int i = lo + tid; i < hi; i += 256) {
        int2 e = pv[i];
        int rl = e.x >> 18;
        int pos = atomicAdd(&loff[rl], 1);
        packed[pos] = make_int2(e.x & 0x3FFFF, e.y);
    }
}

// ---------------------------------------------------------------------------
// Convert concat(uEmb,iEmb) fp32 -> bf16 table (4 elems / thread)
// ---------------------------------------------------------------------------
__global__ __launch_bounds__(256) void cvt_feat0(const float4* __restrict__ a, int na4,
                                                 const float4* __restrict__ b, int nb4,
                                                 ushort4* __restrict__ dst) {
    int i = blockIdx.x * 256 + threadIdx.x;
    if (i >= na4 + nb4) return;
    float4 v = (i < na4) ? a[i] : b[i - na4];
    ushort4 o;
    o.x = f2bf(v.x); o.y = f2bf(v.y); o.z = f2bf(v.z); o.w = f2bf(v.w);
    dst[i] = o;
}

// ---------------------------------------------------------------------------
// Z = X @ W   (X: bf16 table [n x 64], W: fp32 [64 x 64], Z: bf16 [n x 64])
// ((L+I)X)W == (L+I)(XW): GEMM before spmm; all inner-loop reads are LDS.
// ---------------------------------------------------------------------------
__global__ __launch_bounds__(256) void gemm_table_bf16(const unsigned* __restrict__ Xh,
                                                       const float* __restrict__ W,
                                                       unsigned short* __restrict__ Zh,
                                                       int n_rows) {
    __shared__ float Wl[64 * 64];        // 16 KB
    __shared__ uint4 Xl4[64 * 8];        // 8 KB: 64 rows x 32 uints (bf16x2)
    int tid = threadIdx.x;
    int lane = tid & 63;
    int wave = tid >> 6;
    int r0 = blockIdx.x * 64;
    int nr = n_rows - r0; if (nr > 64) nr = 64;

    for (int i = tid; i < 64 * 64; i += 256) Wl[i] = W[i];
    const uint4* Xg4 = (const uint4*)(Xh + (size_t)r0 * 32);
    for (int i = tid; i < nr * 8; i += 256) Xl4[i] = Xg4[i];
    __syncthreads();

    const unsigned* Xl = (const unsigned*)Xl4;
    int rbase = wave * 16;
    float acc[16];
#pragma unroll
    for (int i = 0; i < 16; ++i) acc[i] = 0.f;

#pragma unroll 1
    for (int kc = 0; kc < 8; ++kc) {     // 8 k-values per chunk
        float w0 = Wl[(kc * 8 + 0) * 64 + lane];
        float w1 = Wl[(kc * 8 + 1) * 64 + lane];
        float w2 = Wl[(kc * 8 + 2) * 64 + lane];
        float w3 = Wl[(kc * 8 + 3) * 64 + lane];
        float w4 = Wl[(kc * 8 + 4) * 64 + lane];
        float w5 = Wl[(kc * 8 + 5) * 64 + lane];
        float w6 = Wl[(kc * 8 + 6) * 64 + lane];
        float w7 = Wl[(kc * 8 + 7) * 64 + lane];
#pragma unroll
        for (int i = 0; i < 16; ++i) {
            uint4 q = *(const uint4*)&Xl[(rbase + i) * 32 + kc * 4];  // broadcast
            acc[i] = fmaf(bflo(q.x), w0, acc[i]);
            acc[i] = fmaf(bfhi(q.x), w1, acc[i]);
            acc[i] = fmaf(bflo(q.y), w2, acc[i]);
            acc[i] = fmaf(bfhi(q.y), w3, acc[i]);
            acc[i] = fmaf(bflo(q.z), w4, acc[i]);
            acc[i] = fmaf(bfhi(q.z), w5, acc[i]);
            acc[i] = fmaf(bflo(q.w), w6, acc[i]);
            acc[i] = fmaf(bfhi(q.w), w7, acc[i]);
        }
    }
#pragma unroll
    for (int i = 0; i < 16; ++i) {
        int r = r0 + rbase + i;
        if (r < n_rows) Zh[(size_t)r * 64 + lane] = f2bf(acc[i]);
    }
}

// ---------------------------------------------------------------------------
// SPMM + bias + relu: out[r] = relu( Z[r] + sum_edges v * Z[c] + bias ), bf16.
// One wave per row; half-wave per edge; bf16x2 per lane (proven structure).
// ---------------------------------------------------------------------------
__global__ __launch_bounds__(256) void spmm_bias_relu(const int* __restrict__ row_ptr,
                                                      const int2* __restrict__ packed,
                                                      const unsigned* __restrict__ zh,  // bf16x2, 32/row
                                                      const float* __restrict__ bias,   // [64] fp32
                                                      unsigned* __restrict__ outh,      // bf16x2, 32/row
                                                      int n_rows) {
    int tid = threadIdx.x;
    int lane = tid & 63;
    int wave = tid >> 6;
    int half = lane >> 5;
    int k = lane & 31;
    int r = blockIdx.x * 4 + wave;
    if (r >= n_rows) return;

    unsigned su = zh[(size_t)r * 32 + k];
    float2 acc;
    acc.x = half ? 0.f : bflo(su);
    acc.y = half ? 0.f : bfhi(su);

    int e = row_ptr[r] + half;
    int end = row_ptr[r + 1];
    for (; e + 6 < end; e += 8) {
        int2 p0 = packed[e + 0];
        int2 p1 = packed[e + 2];
        int2 p2 = packed[e + 4];
        int2 p3 = packed[e + 6];
        unsigned x0 = zh[(size_t)p0.x * 32 + k];
        unsigned x1 = zh[(size_t)p1.x * 32 + k];
        unsigned x2 = zh[(size_t)p2.x * 32 + k];
        unsigned x3 = zh[(size_t)p3.x * 32 + k];
        float v0 = __int_as_float(p0.y), v1 = __int_as_float(p1.y);
        float v2 = __int_as_float(p2.y), v3 = __int_as_float(p3.y);
        acc.x = fmaf(v0, bflo(x0), acc.x); acc.y = fmaf(v0, bfhi(x0), acc.y);
        acc.x = fmaf(v1, bflo(x1), acc.x); acc.y = fmaf(v1, bfhi(x1), acc.y);
        acc.x = fmaf(v2, bflo(x2), acc.x); acc.y = fmaf(v2, bfhi(x2), acc.y);
        acc.x = fmaf(v3, bflo(x3), acc.x); acc.y = fmaf(v3, bfhi(x3), acc.y);
    }
    for (; e < end; e += 2) {
        int2 p = packed[e];
        unsigned x = zh[(size_t)p.x * 32 + k];
        float v = __int_as_float(p.y);
        acc.x = fmaf(v, bflo(x), acc.x);
        acc.y = fmaf(v, bfhi(x), acc.y);
    }

    acc.x += __shfl_xor(acc.x, 32, 64);
    acc.y += __shfl_xor(acc.y, 32, 64);
    if (!half) {
        float2 bv = *(const float2*)(bias + 2 * k);
        float ox = fmaxf(acc.x + bv.x, 0.f);
        float oy = fmaxf(acc.y + bv.y, 0.f);
        outh[(size_t)r * 32 + k] = ((unsigned)f2bf(oy) << 16) | (unsigned)f2bf(ox);
    }
}

// ---------------------------------------------------------------------------
// Gather concatenated per-sample features -> bf16 E (one 384-thread block/row)
// ---------------------------------------------------------------------------
__global__ __launch_bounds__(384) void gather_e(const int* __restrict__ userIdx,
                                                const int* __restrict__ itemIdx,
                                                const float* __restrict__ uEmb,
                                                const float* __restrict__ iEmb,
                                                const unsigned short* __restrict__ feat1h,
                                                const unsigned short* __restrict__ feat2h,
                                                unsigned short* __restrict__ E) {
    int b = blockIdx.x;
    int j = threadIdx.x;          // 0..383
    int half = j >= 192;
    int jj = half ? (j - 192) : j;
    int seg = jj >> 6;
    int k = jj & 63;
    unsigned short v;
    if (half == 0) {
        int u = userIdx[b];
        if (seg == 0)      v = f2bf(uEmb[(size_t)u * 64 + k]);
        else if (seg == 1) v = feat1h[(size_t)u * 64 + k];
        else               v = feat2h[(size_t)u * 64 + k];
    } else {
        int it = itemIdx[b];
        if (seg == 0)      v = f2bf(iEmb[(size_t)it * 64 + k]);
        else if (seg == 1) v = feat1h[(size_t)(it + NUM_USERS) * 64 + k];
        else               v = feat2h[(size_t)(it + NUM_USERS) * 64 + k];
    }
    E[(size_t)b * D_CAT + j] = v;
}

// ---------------------------------------------------------------------------
// H1[r][c] = relu( b1[c] + sum_{k<384} E[r][k] * W1[k][c] ), E bf16.
// ---------------------------------------------------------------------------
__global__ __launch_bounds__(256) void gemm384_bf16_relu(const unsigned short* __restrict__ E,
                                                         const float* __restrict__ W,
                                                         const float* __restrict__ bia,
                                                         float* __restrict__ H1,
                                                         int n_rows) {
    __shared__ float Wl[128 * 64];   // 32 KB
    int tid = threadIdx.x;
    int lane = tid & 63;
    int wave = tid >> 6;
    int r0 = blockIdx.x * 64 + wave * 16;
    int last = n_rows - 1;

    const unsigned short* rowp[16];
#pragma unroll
    for (int i = 0; i < 16; ++i) {
        int r = r0 + i;
        r = r > last ? last : r;
        rowp[i] = E + (size_t)r * D_CAT;
    }
    float acc[16];
    float bv = bia[lane];
#pragma unroll
    for (int i = 0; i < 16; ++i) acc[i] = bv;

    for (int k0 = 0; k0 < D_CAT; k0 += 128) {
        if (k0) __syncthreads();
        for (int i = tid; i < 128 * 64; i += 256) Wl[i] = W[k0 * 64 + i];
        __syncthreads();
#pragma unroll 1
        for (int k = 0; k < 128; k += 8) {
            float w0 = Wl[(k + 0) * 64 + lane];
            float w1 = Wl[(k + 1) * 64 + lane];
            float w2 = Wl[(k + 2) * 64 + lane];
            float w3 = Wl[(k + 3) * 64 + lane];
            float w4 = Wl[(k + 4) * 64 + lane];
            float w5 = Wl[(k + 5) * 64 + lane];
            float w6 = Wl[(k + 6) * 64 + lane];
            float w7 = Wl[(k + 7) * 64 + lane];
#pragma unroll
            for (int i = 0; i < 16; ++i) {
                uint4 q = *(const uint4*)(rowp[i] + k0 + k);
                acc[i] = fmaf(bflo(q.x), w0, acc[i]);
                acc[i] = fmaf(bfhi(q.x), w1, acc[i]);
                acc[i] = fmaf(bflo(q.y), w2, acc[i]);
                acc[i] = fmaf(bfhi(q.y), w3, acc[i]);
                acc[i] = fmaf(bflo(q.z), w4, acc[i]);
                acc[i] = fmaf(bfhi(q.z), w5, acc[i]);
                acc[i] = fmaf(bflo(q.w), w6, acc[i]);
                acc[i] = fmaf(bfhi(q.w), w7, acc[i]);
            }
        }
    }
#pragma unroll
    for (int i = 0; i < 16; ++i) {
        int r = r0 + i;
        if (r < n_rows) H1[(size_t)r * 64 + lane] = fmaxf(acc[i], 0.f);
    }
}

// ---------------------------------------------------------------------------
// Fused last two layers: z = H1@W2 + b2 (no relu); out = z@W3 + b3
// ---------------------------------------------------------------------------
__global__ __launch_bounds__(256) void mlp23(const float* __restrict__ H1,
                                             const float* __restrict__ W2,
                                             const float* __restrict__ b2,
                                             const float* __restrict__ W3,
                                             const float* __restrict__ b3,
                                             float* __restrict__ out) {
    __shared__ float Wl[64 * 32];
    __shared__ float w3l[32];
    __shared__ float b2l[32];
    int tid = threadIdx.x;
    for (int i = tid; i < 64 * 32; i += 256) Wl[i] = W2[i];
    if (tid < 32) { w3l[tid] = W3[tid]; b2l[tid] = b2[tid]; }
    __syncthreads();

    int lane = tid & 63;
    int wave = tid >> 6;
    int half = lane >> 5;
    int k = lane & 31;
    int gpair = blockIdx.x * 4 + wave;
    int npairs = gridDim.x * 4;
    float b3v = b3[0];
    for (int p = gpair; p * 2 < BATCH; p += npairs) {
        int r = p * 2 + half;
        float acc = b2l[k];
#pragma unroll
        for (int j = 0; j < 64; ++j)
            acc += H1[(size_t)r * 64 + j] * Wl[j * 32 + k];
        acc = acc * w3l[k];
#pragma unroll
        for (int off = 16; off; off >>= 1)
            acc += __shfl_xor(acc, off, 64);
        if (k == 0) out[r] = acc + b3v;
    }
}

// ---------------------------------------------------------------------------
extern "C" void kernel_launch(void* const* d_in, const int* in_sizes, int n_in,
                              void* d_out, int out_size, void* d_ws, size_t ws_size,
                              hipStream_t stream) {
    const int*   userIdx = (const int*)  d_in[0];
    const int*   itemIdx = (const int*)  d_in[1];
    const int*   lap_rows= (const int*)  d_in[2];
    const int*   lap_cols= (const int*)  d_in[3];
    const float* lap_vals= (const float*)d_in[4];
    const float* uEmb    = (const float*)d_in[5];
    const float* iEmb    = (const float*)d_in[6];
    const float* gW0     = (const float*)d_in[7];
    const float* gb0     = (const float*)d_in[8];
    const float* gW1     = (const float*)d_in[9];
    const float* gb1     = (const float*)d_in[10];
    const float* W1      = (const float*)d_in[11];
    const float* b1      = (const float*)d_in[12];
    const float* W2      = (const float*)d_in[13];
    const float* b2      = (const float*)d_in[14];
    const float* W3      = (const float*)d_in[15];
    const float* b3      = (const float*)d_in[16];
    float* out = (float*)d_out;

    const size_t NF = (size_t)N_NODES * EMB;              // 9.6M elements
    char* w = (char*)d_ws;
    unsigned short* bufA = (unsigned short*)w;            // feat0h/feat1h (19.2 MB)
    unsigned short* bufB = bufA + NF;                     // feat2h (19.2 MB)
    char*  region3 = (char*)(bufB + NF);                  // 38.4 MB multi-use
    // region3 uses (all sequential, no overlap in time):
    int2*  pv      = (int2*)region3;                      // CSR build (19.2 MB)
    unsigned short* Zh = (unsigned short*)region3;        // Z table (19.2 MB)
    unsigned short* E  = (unsigned short*)region3;        // [BATCH,384] bf16 (12.6 MB)
    float* H1 = (float*)(E + (size_t)BATCH * D_CAT);      // [BATCH,64] fp32
    int2*  packed  = (int2*)(region3 + NF * sizeof(float)); // 19.2 MB
    int*   row_ptr = (int*)(packed + NNZ);                // N_NODES+1
    int*   boffs   = row_ptr + (N_NODES + 1);             // NBUCK+1 (immutable)
    int*   gtails  = boffs + (NBUCK + 1);                 // NBUCK (mutable tails)
    int*   bcnt    = gtails + NBUCK;                      // NBUCK

    const int edge_grid = (NNZ + 255) / 256;              // 9375
    const int ms_grid   = (NNZ + EPB - 1) / EPB;          // 293
    const int spmm_grid = (N_NODES + 3) / 4;              // 37500
    const int gemm_grid = (N_NODES + 63) / 64;            // 2344
    const int cvt_grid  = (int)((NF / 4 + 255) / 256);    // 9375
    (void)edge_grid;

    // ---- Build CSR via LDS-multisplit counting sort (shared by both layers)
    hipMemsetAsync(bcnt, 0, NBUCK * sizeof(int), stream);
    bucket_hist<<<128, 1024, 0, stream>>>(lap_rows, bcnt, NNZ);
    bucket_scan<<<1, 1024, 0, stream>>>(bcnt, boffs, gtails, NNZ);
    coarse_multisplit<<<ms_grid, 1024, 0, stream>>>(lap_rows, lap_cols, lap_vals,
                                                    gtails, pv, NNZ);
    fine_scatter<<<NBUCK, 256, 0, stream>>>(boffs, pv, packed, row_ptr, NNZ);

    // ---- feat0h = bf16(concat(uEmb, iEmb))
    cvt_feat0<<<cvt_grid, 256, 0, stream>>>((const float4*)uEmb, NUM_USERS * EMB / 4,
                                            (const float4*)iEmb, NUM_ITEMS * EMB / 4,
                                            (ushort4*)bufA);

    // ---- Layer 1 (reordered): Z = feat0@gW0 ; feat1 = relu((L+I)Z + gb0)
    gemm_table_bf16<<<gemm_grid, 256, 0, stream>>>((const unsigned*)bufA, gW0, Zh, N_NODES);
    spmm_bias_relu<<<spmm_grid, 256, 0, stream>>>(row_ptr, packed, (const unsigned*)Zh,
                                                  gb0, (unsigned*)bufA, N_NODES);

    // ---- Layer 2: Z = feat1@gW1 ; feat2 = relu((L+I)Z + gb1)
    gemm_table_bf16<<<gemm_grid, 256, 0, stream>>>((const unsigned*)bufA, gW1, Zh, N_NODES);
    spmm_bias_relu<<<spmm_grid, 256, 0, stream>>>(row_ptr, packed, (const unsigned*)Zh,
                                                  gb1, (unsigned*)bufB, N_NODES);

    // ---- Gather per-sample concatenated features (E overlays region3; Z dead)
    gather_e<<<BATCH, 384, 0, stream>>>(userIdx, itemIdx, uEmb, iEmb, bufA, bufB, E);

    // ---- MLP
    gemm384_bf16_relu<<<(BATCH + 63) / 64, 256, 0, stream>>>(E, W1, b1, H1, BATCH);
    mlp23<<<512, 256, 0, stream>>>(H1, W2, b2, W3, b3, out);
}